// Round 4
// baseline (349.829 us; speedup 1.0000x reference)
//
#include <hip/hip_runtime.h>
#include <hip/hip_bf16.h>
#include <math.h>

#define L_    4096
#define C96   96
#define DI_   192
#define Nn    16
#define Rr    6
#define Kk    4
#define HW_   64
#define HF_   255
#define CH_   64
#define NCH_  64

__device__ __forceinline__ float sp_softplus(float s) {
    return fmaxf(s, 0.f) + log1pf(expf(-fabsf(s)));
}
__device__ __forceinline__ float sp_silu(float s) {
    return s / (1.f + expf(-s));
}
// quad-perm DPP shuffles (full-rate VALU, lanes within quad)
__device__ __forceinline__ float qxor1(float x) {
    return __int_as_float(__builtin_amdgcn_update_dpp(0, __float_as_int(x),
                                                      0xB1, 0xF, 0xF, true));
}
__device__ __forceinline__ float qxor2(float x) {
    return __int_as_float(__builtin_amdgcn_update_dpp(0, __float_as_int(x),
                                                      0x4E, 0xF, 0xF, true));
}

// K1: RMS-LN over C=96 channels (per spatial position). n1 layout (c, l).
__global__ void k_rmsln1(const float* __restrict__ x, const float* __restrict__ w,
                         const float* __restrict__ b, float* __restrict__ n1) {
    int l = blockIdx.x * blockDim.x + threadIdx.x;
    if (l >= L_) return;
    float ss = 0.f;
    for (int c = 0; c < C96; ++c) { float v = x[c * L_ + l]; ss += v * v; }
    float r = rsqrtf(ss * (1.f / C96) + 1e-6f);
    for (int c = 0; c < C96; ++c)
        n1[c * L_ + l] = x[c * L_ + l] * r * w[c] + b[c];
}

// K2: in_proj GEMM: xzT[o, l] = sum_c n1[c,l] * W[o,c].  O=384. 8-way o blocking.
__global__ void k_inproj(const float* __restrict__ n1, const float* __restrict__ W,
                         float* __restrict__ xzT) {
    int l = blockIdx.x * 64 + threadIdx.x;
    int o0 = (blockIdx.y * 4 + threadIdx.y) * 8;
    float acc[8] = {0.f, 0.f, 0.f, 0.f, 0.f, 0.f, 0.f, 0.f};
    for (int c = 0; c < C96; ++c) {
        float v = n1[c * L_ + l];
#pragma unroll
        for (int j = 0; j < 8; ++j) acc[j] += v * W[(o0 + j) * C96 + c];
    }
#pragma unroll
    for (int j = 0; j < 8; ++j) xzT[(o0 + j) * L_ + l] = acc[j];
}

// K3: depthwise 3x3 conv (SAME) + bias + SiLU on xc (192, 64, 64).
__global__ void k_conv192(const float* __restrict__ xc, const float* __restrict__ w,
                          const float* __restrict__ b, float* __restrict__ out) {
    int idx = blockIdx.x * 256 + threadIdx.x;
    if (idx >= DI_ * L_) return;
    int c = idx / L_, l = idx % L_;
    int h = l >> 6, wc = l & 63;
    float s = b[c];
#pragma unroll
    for (int di = -1; di <= 1; ++di)
#pragma unroll
        for (int dj = -1; dj <= 1; ++dj) {
            int hh = h + di, ww = wc + dj;
            if (hh >= 0 && hh < HW_ && ww >= 0 && ww < HW_)
                s += xc[c * L_ + hh * HW_ + ww] * w[c * 9 + (di + 1) * 3 + (dj + 1)];
        }
    out[idx] = sp_silu(s);
}

// K4: materialize 4 direction views xs[(k*DI+d)*L + l]
__global__ void k_build_xs(const float* __restrict__ xconv, float* __restrict__ xs) {
    int idx = blockIdx.x * 256 + threadIdx.x;
    if (idx >= Kk * DI_ * L_) return;
    int l = idx % L_; int kd = idx / L_; int d = kd % DI_; int k = kd / DI_;
    int ll = (k & 2) ? (L_ - 1 - l) : l;
    int pos = (k & 1) ? ((ll & 63) * 64 + (ll >> 6)) : ll;
    xs[idx] = xconv[d * L_ + pos];
}

// K5: x_proj GEMM fused with B/C transpose. Block=256: one k, 64-wide l tile.
__global__ __launch_bounds__(256) void k_xdbl2(const float* __restrict__ xs,
        const float* __restrict__ Wxp, float* __restrict__ dts,
        float* __restrict__ BsT, float* __restrict__ CsT) {
    __shared__ float sx[DI_][64];
    int k = blockIdx.y;
    int l0 = blockIdx.x * 64;
    int t = threadIdx.x;
    const float* src = xs + (k * DI_) * L_ + l0;
    for (int i = t; i < DI_ * 64; i += 256) {
        int d = i >> 6, l = i & 63;
        sx[d][l] = src[d * L_ + l];
    }
    __syncthreads();
    int l = t & 63, cg = t >> 6;
    int c0 = cg * 10;
    int cnt = (cg == 3) ? 8 : 10;
    float acc[10] = {0.f, 0.f, 0.f, 0.f, 0.f, 0.f, 0.f, 0.f, 0.f, 0.f};
    const float* Wk = Wxp + k * 38 * DI_;
    for (int d = 0; d < DI_; ++d) {
        float v = sx[d][l];
#pragma unroll
        for (int j = 0; j < 10; ++j) {
            int cj = c0 + j; if (cj > 37) cj = 37;
            acc[j] += v * Wk[cj * DI_ + d];
        }
    }
    int gl = l0 + l;
#pragma unroll
    for (int j = 0; j < 10; ++j) {
        if (j < cnt) {
            int c = c0 + j;
            float v = acc[j];
            if (c < Rr)           dts[(k * Rr + c) * L_ + gl] = v;
            else if (c < Rr + Nn) BsT[(k * L_ + gl) * Nn + (c - Rr)] = v;
            else                  CsT[(k * L_ + gl) * Nn + (c - Rr - Nn)] = v;
        }
    }
}

// K6: delta[kd, l] = softplus(sum_r dts[k,r,l] * dtw[kd,r] + dtb[kd])
__global__ void k_delta(const float* __restrict__ dts, const float* __restrict__ dtw,
                        const float* __restrict__ dtb, float* __restrict__ delta) {
    int idx = blockIdx.x * 256 + threadIdx.x;
    if (idx >= Kk * DI_ * L_) return;
    int l = idx % L_; int kd = idx / L_; int k = kd / DI_;
    float s = dtb[kd];
#pragma unroll
    for (int r = 0; r < Rr; ++r)
        s += dts[(k * Rr + r) * L_ + l] * dtw[kd * Rr + r];
    delta[idx] = sp_softplus(s);
}

// K8: scan phase 1 — 4 lanes per (kd,chunk), each lane owns 4 n's.
__global__ __launch_bounds__(256) void k_scan1(const float* __restrict__ delta,
        const float* __restrict__ xs, const float* __restrict__ BsT,
        const float* __restrict__ A_logs, float* __restrict__ P,
        float* __restrict__ S) {
    int g = blockIdx.x * 64 + (threadIdx.x >> 2);
    int j = threadIdx.x & 3;
    int chunk = g & (NCH_ - 1); int kd = g >> 6; int k = kd / DI_;
    float4 Al = *(const float4*)&A_logs[kd * Nn + 4 * j];
    float A0 = -__expf(Al.x), A1 = -__expf(Al.y), A2 = -__expf(Al.z), A3 = -__expf(Al.w);
    float h0 = 0.f, h1 = 0.f, h2 = 0.f, h3 = 0.f;
    float p0 = 1.f, p1 = 1.f, p2 = 1.f, p3 = 1.f;
    int base = kd * L_ + chunk * CH_;
    const float4* Bv = (const float4*)&BsT[(k * L_ + chunk * CH_) * Nn + 4 * j];
#pragma unroll 2
    for (int i = 0; i < CH_; ++i) {
        float dl = delta[base + i];
        float ul = xs[base + i];
        float4 bv = Bv[i * 4];
        float du = dl * ul;
        float e0 = __expf(dl * A0), e1 = __expf(dl * A1);
        float e2 = __expf(dl * A2), e3 = __expf(dl * A3);
        h0 = e0 * h0 + du * bv.x; h1 = e1 * h1 + du * bv.y;
        h2 = e2 * h2 + du * bv.z; h3 = e3 * h3 + du * bv.w;
        p0 *= e0; p1 *= e1; p2 *= e2; p3 *= e3;
    }
    int o = g * Nn + 4 * j;
    *(float4*)&P[o] = make_float4(p0, p1, p2, p3);
    *(float4*)&S[o] = make_float4(h0, h1, h2, h3);
}

// K9: scan phase 2 — exclusive prefix over 64 chunks per (kd, n).
__global__ void k_scan2(const float* __restrict__ P, const float* __restrict__ S,
                        float* __restrict__ HS) {
    int t = blockIdx.x * 256 + threadIdx.x;
    int kd = t >> 4; int n = t & 15;
    if (kd >= Kk * DI_) return;
    float h = 0.f;
    for (int c = 0; c < NCH_; ++c) {
        int o = (kd * NCH_ + c) * Nn + n;
        HS[o] = h;
        h = P[o] * h + S[o];
    }
}

// K10: scan phase 3 — 4 lanes per (kd,chunk); DPP quad reduce; writes
// scan_y in ORIGINAL image coordinates (direction mapping at store).
__global__ __launch_bounds__(256) void k_scan3(const float* __restrict__ delta,
        const float* __restrict__ xs, const float* __restrict__ BsT,
        const float* __restrict__ CsT, const float* __restrict__ A_logs,
        const float* __restrict__ Ds, const float* __restrict__ HS,
        float* __restrict__ scan_y) {
    int g = blockIdx.x * 64 + (threadIdx.x >> 2);
    int j = threadIdx.x & 3;
    int chunk = g & (NCH_ - 1); int kd = g >> 6; int k = kd / DI_;
    float4 Al = *(const float4*)&A_logs[kd * Nn + 4 * j];
    float A0 = -__expf(Al.x), A1 = -__expf(Al.y), A2 = -__expf(Al.z), A3 = -__expf(Al.w);
    float Dp = Ds[kd];
    float4 hv = *(const float4*)&HS[(kd * NCH_ + chunk) * Nn + 4 * j];
    float h0 = hv.x, h1 = hv.y, h2 = hv.z, h3 = hv.w;
    int base = kd * L_ + chunk * CH_;
    int lbase = chunk * CH_;
    const float4* Bv = (const float4*)&BsT[(k * L_ + lbase) * Nn + 4 * j];
    const float4* Cv = (const float4*)&CsT[(k * L_ + lbase) * Nn + 4 * j];
    float* yout = scan_y + kd * L_;
#pragma unroll 2
    for (int i = 0; i < CH_; ++i) {
        float dl = delta[base + i];
        float ul = xs[base + i];
        float4 bv = Bv[i * 4];
        float4 cv = Cv[i * 4];
        float du = dl * ul;
        float e0 = __expf(dl * A0), e1 = __expf(dl * A1);
        float e2 = __expf(dl * A2), e3 = __expf(dl * A3);
        h0 = e0 * h0 + du * bv.x; h1 = e1 * h1 + du * bv.y;
        h2 = e2 * h2 + du * bv.z; h3 = e3 * h3 + du * bv.w;
        float ps = h0 * cv.x + h1 * cv.y + h2 * cv.z + h3 * cv.w;
        ps += qxor1(ps);
        ps += qxor2(ps);
        if (j == 0) {
            int sl = lbase + i;
            int ll = (k & 2) ? (L_ - 1 - sl) : sl;
            int p  = (k & 1) ? (((ll & 63) << 6) | (ll >> 6)) : ll;
            yout[p] = ps + Dp * ul;
        }
    }
}

// K11v2: l-fast combine. Block = 64 l's x 256 threads (4 channel groups).
// 4-dir sum + LayerNorm(192) + silu(z) gate (all via LDS tile) +
// out_proj GEMM (24 c/thread, scalar W loads) + residual + RMSNorm2.
__global__ __launch_bounds__(256) void k_combine2(
        const float* __restrict__ scan_y, const float* __restrict__ onw,
        const float* __restrict__ onb, const float* __restrict__ xzT,
        const float* __restrict__ Wout, const float* __restrict__ x,
        const float* __restrict__ w2, const float* __restrict__ b2,
        float* __restrict__ x2, float* __restrict__ n2) {
    __shared__ float yt[DI_][65];
    __shared__ float red[4][64];
    int l0 = blockIdx.x * 64;
    int t = threadIdx.x;
    int l = t & 63, g = t >> 6;
    // stage 4-direction sum, d in [g*48, g*48+48)
    float psum = 0.f;
    for (int d = g * 48; d < g * 48 + 48; ++d) {
        float y = scan_y[(0 * DI_ + d) * L_ + l0 + l]
                + scan_y[(1 * DI_ + d) * L_ + l0 + l]
                + scan_y[(2 * DI_ + d) * L_ + l0 + l]
                + scan_y[(3 * DI_ + d) * L_ + l0 + l];
        yt[d][l] = y;
        psum += y;
    }
    red[g][l] = psum;
    __syncthreads();
    float mu = (red[0][l] + red[1][l] + red[2][l] + red[3][l]) * (1.f / DI_);
    float pv = 0.f;
    for (int d = g * 48; d < g * 48 + 48; ++d) {
        float yc = yt[d][l] - mu;
        pv += yc * yc;
    }
    __syncthreads();
    red[g][l] = pv;
    __syncthreads();
    float var = (red[0][l] + red[1][l] + red[2][l] + red[3][l]) * (1.f / DI_);
    float rstd = rsqrtf(var + 1e-5f);
    for (int d = g * 48; d < g * 48 + 48; ++d) {
        float zv = xzT[(DI_ + d) * L_ + l0 + l];
        float yn = (yt[d][l] - mu) * rstd * onw[d] + onb[d];
        yt[d][l] = yn * sp_silu(zv);
    }
    __syncthreads();
    // out_proj: c in [g*24, g*24+24)
    float acc[24];
#pragma unroll
    for (int j = 0; j < 24; ++j) acc[j] = 0.f;
    const float* Wc = Wout + (g * 24) * DI_;
    for (int d = 0; d < DI_; ++d) {
        float yv = yt[d][l];
#pragma unroll
        for (int j = 0; j < 24; ++j) acc[j] += yv * Wc[j * DI_ + d];
    }
    float ss = 0.f;
    float x2v[24];
#pragma unroll
    for (int j = 0; j < 24; ++j) {
        int c = g * 24 + j;
        float v = x[c * L_ + l0 + l] + acc[j];
        x2v[j] = v; ss += v * v;
        x2[c * L_ + l0 + l] = v;
    }
    __syncthreads();
    red[g][l] = ss;
    __syncthreads();
    float r2 = rsqrtf((red[0][l] + red[1][l] + red[2][l] + red[3][l]) * (1.f / C96)
                      + 1e-6f);
#pragma unroll
    for (int j = 0; j < 24; ++j) {
        int c = g * 24 + j;
        n2[c * L_ + l0 + l] = x2v[j] * r2 * w2[c] + b2[c];
    }
}

// K12: EDFFN pin GEMM: hf[o, l] = sum_c n2[c,l] * W[o,c].  O=510.
__global__ void k_pin(const float* __restrict__ n2, const float* __restrict__ W,
                      float* __restrict__ hf) {
    int l = blockIdx.x * 64 + threadIdx.x;
    int g = blockIdx.y * 4 + threadIdx.y;
    if (g >= 51) return;
    int o0 = g * 10;
    float acc[10] = {0.f, 0.f, 0.f, 0.f, 0.f, 0.f, 0.f, 0.f, 0.f, 0.f};
    for (int c = 0; c < C96; ++c) {
        float v = n2[c * L_ + l];
#pragma unroll
        for (int j = 0; j < 10; ++j) acc[j] += v * W[(o0 + j) * C96 + c];
    }
#pragma unroll
    for (int j = 0; j < 10; ++j) hf[(o0 + j) * L_ + l] = acc[j];
}

// K13: depthwise 3x3 (no bias) on 510 channels + GELU(h1)*h2 gate.
__global__ void k_ffnconv(const float* __restrict__ hf, const float* __restrict__ w,
                          float* __restrict__ g) {
    int idx = blockIdx.x * 256 + threadIdx.x;
    if (idx >= HF_ * L_) return;
    int c = idx / L_, l = idx % L_;
    int h = l >> 6, wc = l & 63;
    float s1 = 0.f, s2 = 0.f;
#pragma unroll
    for (int di = -1; di <= 1; ++di)
#pragma unroll
        for (int dj = -1; dj <= 1; ++dj) {
            int hh = h + di, ww = wc + dj;
            if (hh >= 0 && hh < HW_ && ww >= 0 && ww < HW_) {
                int p = hh * HW_ + ww;
                int widx = (di + 1) * 3 + (dj + 1);
                s1 += hf[c * L_ + p] * w[c * 9 + widx];
                s2 += hf[(c + HF_) * L_ + p] * w[(c + HF_) * 9 + widx];
            }
        }
    float ge = 0.5f * s1 * (1.f + erff(s1 * 0.70710678118654752f));
    g[idx] = ge * s2;
}

// K14: pout GEMM + final residual.
__global__ void k_pout(const float* __restrict__ g, const float* __restrict__ W,
                       const float* __restrict__ x2, float* __restrict__ out) {
    int l = blockIdx.x * 64 + threadIdx.x;
    int c0 = (blockIdx.y * 4 + threadIdx.y) * 8;
    float acc[8] = {0.f, 0.f, 0.f, 0.f, 0.f, 0.f, 0.f, 0.f};
    for (int i = 0; i < HF_; ++i) {
        float v = g[i * L_ + l];
#pragma unroll
        for (int j = 0; j < 8; ++j) acc[j] += v * W[(c0 + j) * HF_ + i];
    }
#pragma unroll
    for (int j = 0; j < 8; ++j)
        out[(c0 + j) * L_ + l] = x2[(c0 + j) * L_ + l] + acc[j];
}

extern "C" void kernel_launch(void* const* d_in, const int* in_sizes, int n_in,
                              void* d_out, int out_size, void* d_ws, size_t ws_size,
                              hipStream_t stream) {
    const float* x         = (const float*)d_in[0];
    const float* norm1_w   = (const float*)d_in[1];
    const float* norm1_b   = (const float*)d_in[2];
    const float* in_proj_w = (const float*)d_in[3];
    const float* conv2d_w  = (const float*)d_in[4];
    const float* conv2d_b  = (const float*)d_in[5];
    const float* x_proj_w  = (const float*)d_in[6];
    const float* dt_projs_w= (const float*)d_in[7];
    const float* dt_projs_b= (const float*)d_in[8];
    const float* A_logs    = (const float*)d_in[9];
    const float* Ds        = (const float*)d_in[10];
    const float* out_norm_w= (const float*)d_in[11];
    const float* out_norm_b= (const float*)d_in[12];
    const float* out_proj_w= (const float*)d_in[13];
    const float* norm2_w   = (const float*)d_in[14];
    const float* norm2_b   = (const float*)d_in[15];
    const float* pin_w     = (const float*)d_in[16];
    const float* dw_w      = (const float*)d_in[17];
    const float* pout_w    = (const float*)d_in[18];

    float* ws = (float*)d_ws;
    float* n1     = ws; ws += C96 * L_;          // reused as dtsb after inproj
    float* xzT    = ws; ws += 2 * DI_ * L_;
    float* xconv  = ws; ws += DI_ * L_;
    float* xs     = ws; ws += Kk * DI_ * L_;     // reused as hf after scan3
    float* delta  = ws; ws += Kk * DI_ * L_;     // reused as gbuf after scan3
    float* BsT    = ws; ws += Kk * L_ * Nn;
    float* CsT    = ws; ws += Kk * L_ * Nn;
    float* Pw     = ws; ws += Kk * DI_ * NCH_ * Nn;
    float* Sw     = ws; ws += Kk * DI_ * NCH_ * Nn;
    float* HS     = ws; ws += Kk * DI_ * NCH_ * Nn;
    float* scan_y = ws; ws += Kk * DI_ * L_;
    float* x2     = ws; ws += C96 * L_;
    float* n2     = ws; ws += C96 * L_;
    float* dtsb   = n1;
    float* hf     = xs;
    float* gbuf   = delta;

    dim3 b64x4(64, 4, 1);

    k_rmsln1<<<16, 256, 0, stream>>>(x, norm1_w, norm1_b, n1);
    k_inproj<<<dim3(64, 12), b64x4, 0, stream>>>(n1, in_proj_w, xzT);
    k_conv192<<<3072, 256, 0, stream>>>(xzT, conv2d_w, conv2d_b, xconv);
    k_build_xs<<<12288, 256, 0, stream>>>(xconv, xs);
    k_xdbl2<<<dim3(64, 4), 256, 0, stream>>>(xs, x_proj_w, dtsb, BsT, CsT);
    k_delta<<<12288, 256, 0, stream>>>(dtsb, dt_projs_w, dt_projs_b, delta);
    k_scan1<<<768, 256, 0, stream>>>(delta, xs, BsT, A_logs, Pw, Sw);
    k_scan2<<<48, 256, 0, stream>>>(Pw, Sw, HS);
    k_scan3<<<768, 256, 0, stream>>>(delta, xs, BsT, CsT, A_logs, Ds, HS, scan_y);
    k_combine2<<<64, 256, 0, stream>>>(scan_y, out_norm_w, out_norm_b, xzT,
                                       out_proj_w, x, norm2_w, norm2_b, x2, n2);
    k_pin<<<dim3(64, 13), b64x4, 0, stream>>>(n2, pin_w, hf);
    k_ffnconv<<<4080, 256, 0, stream>>>(hf, dw_w, gbuf);
    k_pout<<<dim3(64, 3), b64x4, 0, stream>>>(gbuf, pout_w, x2, (float*)d_out);
}

// Round 5
// 303.101 us; speedup vs baseline: 1.1542x; 1.1542x over previous
//
#include <hip/hip_runtime.h>
#include <hip/hip_bf16.h>
#include <math.h>

#define L_    4096
#define C96   96
#define DI_   192
#define Nn    16
#define Rr    6
#define Kk    4
#define HW_   64
#define HF_   255
#define CH_   64
#define NCH_  64

__device__ __forceinline__ float sp_softplus(float s) {
    return fmaxf(s, 0.f) + log1pf(expf(-fabsf(s)));
}
__device__ __forceinline__ float sp_silu(float s) {
    return s / (1.f + expf(-s));
}
// quad-perm DPP shuffles (full-rate VALU, lanes within quad)
__device__ __forceinline__ float qxor1(float x) {
    return __int_as_float(__builtin_amdgcn_update_dpp(0, __float_as_int(x),
                                                      0xB1, 0xF, 0xF, true));
}
__device__ __forceinline__ float qxor2(float x) {
    return __int_as_float(__builtin_amdgcn_update_dpp(0, __float_as_int(x),
                                                      0x4E, 0xF, 0xF, true));
}

// K1v2: RMS-LN, l-tile=16, 16 groups x 6 channels. grid=256.
__global__ __launch_bounds__(256) void k_rmsln1(const float* __restrict__ x,
        const float* __restrict__ w, const float* __restrict__ b,
        float* __restrict__ n1) {
    __shared__ float red[16][16];
    int l0 = blockIdx.x * 16;
    int t = threadIdx.x;
    int l = t & 15, g = t >> 4;
    float xv[6];
    float ss = 0.f;
#pragma unroll
    for (int j = 0; j < 6; ++j) {
        int c = g * 6 + j;
        xv[j] = x[c * L_ + l0 + l];
        ss += xv[j] * xv[j];
    }
    red[g][l] = ss;
    __syncthreads();
    float tot = 0.f;
#pragma unroll
    for (int g2 = 0; g2 < 16; ++g2) tot += red[g2][l];
    float r = rsqrtf(tot * (1.f / C96) + 1e-6f);
#pragma unroll
    for (int j = 0; j < 6; ++j) {
        int c = g * 6 + j;
        n1[c * L_ + l0 + l] = xv[j] * r * w[c] + b[c];
    }
}

// K2: in_proj GEMM: xzT[o, l] = sum_c n1[c,l] * W[o,c].  O=384. 8-way o blocking.
__global__ void k_inproj(const float* __restrict__ n1, const float* __restrict__ W,
                         float* __restrict__ xzT) {
    int l = blockIdx.x * 64 + threadIdx.x;
    int o0 = (blockIdx.y * 4 + threadIdx.y) * 8;
    float acc[8] = {0.f, 0.f, 0.f, 0.f, 0.f, 0.f, 0.f, 0.f};
    for (int c = 0; c < C96; ++c) {
        float v = n1[c * L_ + l];
#pragma unroll
        for (int j = 0; j < 8; ++j) acc[j] += v * W[(o0 + j) * C96 + c];
    }
#pragma unroll
    for (int j = 0; j < 8; ++j) xzT[(o0 + j) * L_ + l] = acc[j];
}

// K3: depthwise 3x3 conv (SAME) + bias + SiLU on xc (192, 64, 64).
__global__ void k_conv192(const float* __restrict__ xc, const float* __restrict__ w,
                          const float* __restrict__ b, float* __restrict__ out) {
    int idx = blockIdx.x * 256 + threadIdx.x;
    if (idx >= DI_ * L_) return;
    int c = idx / L_, l = idx % L_;
    int h = l >> 6, wc = l & 63;
    float s = b[c];
#pragma unroll
    for (int di = -1; di <= 1; ++di)
#pragma unroll
        for (int dj = -1; dj <= 1; ++dj) {
            int hh = h + di, ww = wc + dj;
            if (hh >= 0 && hh < HW_ && ww >= 0 && ww < HW_)
                s += xc[c * L_ + hh * HW_ + ww] * w[c * 9 + (di + 1) * 3 + (dj + 1)];
        }
    out[idx] = sp_silu(s);
}

// K4: materialize 4 direction views xs[(k*DI+d)*L + l]
__global__ void k_build_xs(const float* __restrict__ xconv, float* __restrict__ xs) {
    int idx = blockIdx.x * 256 + threadIdx.x;
    if (idx >= Kk * DI_ * L_) return;
    int l = idx % L_; int kd = idx / L_; int d = kd % DI_; int k = kd / DI_;
    int ll = (k & 2) ? (L_ - 1 - l) : l;
    int pos = (k & 1) ? ((ll & 63) * 64 + (ll >> 6)) : ll;
    xs[idx] = xconv[d * L_ + pos];
}

// K5: x_proj GEMM fused with B/C transpose. Block=256: one k, 64-wide l tile.
__global__ __launch_bounds__(256) void k_xdbl2(const float* __restrict__ xs,
        const float* __restrict__ Wxp, float* __restrict__ dts,
        float* __restrict__ BsT, float* __restrict__ CsT) {
    __shared__ float sx[DI_][64];
    int k = blockIdx.y;
    int l0 = blockIdx.x * 64;
    int t = threadIdx.x;
    const float* src = xs + (k * DI_) * L_ + l0;
    for (int i = t; i < DI_ * 64; i += 256) {
        int d = i >> 6, l = i & 63;
        sx[d][l] = src[d * L_ + l];
    }
    __syncthreads();
    int l = t & 63, cg = t >> 6;
    int c0 = cg * 10;
    int cnt = (cg == 3) ? 8 : 10;
    float acc[10] = {0.f, 0.f, 0.f, 0.f, 0.f, 0.f, 0.f, 0.f, 0.f, 0.f};
    const float* Wk = Wxp + k * 38 * DI_;
    for (int d = 0; d < DI_; ++d) {
        float v = sx[d][l];
#pragma unroll
        for (int j = 0; j < 10; ++j) {
            int cj = c0 + j; if (cj > 37) cj = 37;
            acc[j] += v * Wk[cj * DI_ + d];
        }
    }
    int gl = l0 + l;
#pragma unroll
    for (int j = 0; j < 10; ++j) {
        if (j < cnt) {
            int c = c0 + j;
            float v = acc[j];
            if (c < Rr)           dts[(k * Rr + c) * L_ + gl] = v;
            else if (c < Rr + Nn) BsT[(k * L_ + gl) * Nn + (c - Rr)] = v;
            else                  CsT[(k * L_ + gl) * Nn + (c - Rr - Nn)] = v;
        }
    }
}

// K6: delta[kd, l] = softplus(sum_r dts[k,r,l] * dtw[kd,r] + dtb[kd])
__global__ void k_delta(const float* __restrict__ dts, const float* __restrict__ dtw,
                        const float* __restrict__ dtb, float* __restrict__ delta) {
    int idx = blockIdx.x * 256 + threadIdx.x;
    if (idx >= Kk * DI_ * L_) return;
    int l = idx % L_; int kd = idx / L_; int k = kd / DI_;
    float s = dtb[kd];
#pragma unroll
    for (int r = 0; r < Rr; ++r)
        s += dts[(k * Rr + r) * L_ + l] * dtw[kd * Rr + r];
    delta[idx] = sp_softplus(s);
}

// K8: scan phase 1 — 4 lanes per (kd,chunk), each lane owns 4 n's.
__global__ __launch_bounds__(256) void k_scan1(const float* __restrict__ delta,
        const float* __restrict__ xs, const float* __restrict__ BsT,
        const float* __restrict__ A_logs, float* __restrict__ P,
        float* __restrict__ S) {
    int g = blockIdx.x * 64 + (threadIdx.x >> 2);
    int j = threadIdx.x & 3;
    int chunk = g & (NCH_ - 1); int kd = g >> 6; int k = kd / DI_;
    float4 Al = *(const float4*)&A_logs[kd * Nn + 4 * j];
    float A0 = -__expf(Al.x), A1 = -__expf(Al.y), A2 = -__expf(Al.z), A3 = -__expf(Al.w);
    float h0 = 0.f, h1 = 0.f, h2 = 0.f, h3 = 0.f;
    float p0 = 1.f, p1 = 1.f, p2 = 1.f, p3 = 1.f;
    int base = kd * L_ + chunk * CH_;
    const float4* Bv = (const float4*)&BsT[(k * L_ + chunk * CH_) * Nn + 4 * j];
#pragma unroll 2
    for (int i = 0; i < CH_; ++i) {
        float dl = delta[base + i];
        float ul = xs[base + i];
        float4 bv = Bv[i * 4];
        float du = dl * ul;
        float e0 = __expf(dl * A0), e1 = __expf(dl * A1);
        float e2 = __expf(dl * A2), e3 = __expf(dl * A3);
        h0 = e0 * h0 + du * bv.x; h1 = e1 * h1 + du * bv.y;
        h2 = e2 * h2 + du * bv.z; h3 = e3 * h3 + du * bv.w;
        p0 *= e0; p1 *= e1; p2 *= e2; p3 *= e3;
    }
    int o = g * Nn + 4 * j;
    *(float4*)&P[o] = make_float4(p0, p1, p2, p3);
    *(float4*)&S[o] = make_float4(h0, h1, h2, h3);
}

// K9: scan phase 2 — exclusive prefix over 64 chunks per (kd, n).
__global__ void k_scan2(const float* __restrict__ P, const float* __restrict__ S,
                        float* __restrict__ HS) {
    int t = blockIdx.x * 256 + threadIdx.x;
    int kd = t >> 4; int n = t & 15;
    if (kd >= Kk * DI_) return;
    float h = 0.f;
    for (int c = 0; c < NCH_; ++c) {
        int o = (kd * NCH_ + c) * Nn + n;
        HS[o] = h;
        h = P[o] * h + S[o];
    }
}

// K10: scan phase 3 — 4 lanes per (kd,chunk); DPP quad reduce; writes
// scan_y in ORIGINAL image coordinates (direction mapping at store).
__global__ __launch_bounds__(256) void k_scan3(const float* __restrict__ delta,
        const float* __restrict__ xs, const float* __restrict__ BsT,
        const float* __restrict__ CsT, const float* __restrict__ A_logs,
        const float* __restrict__ Ds, const float* __restrict__ HS,
        float* __restrict__ scan_y) {
    int g = blockIdx.x * 64 + (threadIdx.x >> 2);
    int j = threadIdx.x & 3;
    int chunk = g & (NCH_ - 1); int kd = g >> 6; int k = kd / DI_;
    float4 Al = *(const float4*)&A_logs[kd * Nn + 4 * j];
    float A0 = -__expf(Al.x), A1 = -__expf(Al.y), A2 = -__expf(Al.z), A3 = -__expf(Al.w);
    float Dp = Ds[kd];
    float4 hv = *(const float4*)&HS[(kd * NCH_ + chunk) * Nn + 4 * j];
    float h0 = hv.x, h1 = hv.y, h2 = hv.z, h3 = hv.w;
    int base = kd * L_ + chunk * CH_;
    int lbase = chunk * CH_;
    const float4* Bv = (const float4*)&BsT[(k * L_ + lbase) * Nn + 4 * j];
    const float4* Cv = (const float4*)&CsT[(k * L_ + lbase) * Nn + 4 * j];
    float* yout = scan_y + kd * L_;
#pragma unroll 2
    for (int i = 0; i < CH_; ++i) {
        float dl = delta[base + i];
        float ul = xs[base + i];
        float4 bv = Bv[i * 4];
        float4 cv = Cv[i * 4];
        float du = dl * ul;
        float e0 = __expf(dl * A0), e1 = __expf(dl * A1);
        float e2 = __expf(dl * A2), e3 = __expf(dl * A3);
        h0 = e0 * h0 + du * bv.x; h1 = e1 * h1 + du * bv.y;
        h2 = e2 * h2 + du * bv.z; h3 = e3 * h3 + du * bv.w;
        float ps = h0 * cv.x + h1 * cv.y + h2 * cv.z + h3 * cv.w;
        ps += qxor1(ps);
        ps += qxor2(ps);
        if (j == 0) {
            int sl = lbase + i;
            int ll = (k & 2) ? (L_ - 1 - sl) : sl;
            int p  = (k & 1) ? (((ll & 63) << 6) | (ll >> 6)) : ll;
            yout[p] = ps + Dp * ul;
        }
    }
}

// K11v3: l-tile=16, grid=256 blocks, 256 threads = 16 groups x 16 lanes.
// Stage 4-dir sum into l-major LDS yt[16][196] (stride%32=4 -> 2-way = free,
// 16B aligned for float4). LN + silu(z) gate + out_proj (6 c/group,
// d-vectorized float4) + residual + RMSNorm2.
__global__ __launch_bounds__(256) void k_combine3(
        const float* __restrict__ scan_y, const float* __restrict__ onw,
        const float* __restrict__ onb, const float* __restrict__ xzT,
        const float* __restrict__ Wout, const float* __restrict__ x,
        const float* __restrict__ w2, const float* __restrict__ b2,
        float* __restrict__ x2, float* __restrict__ n2) {
    __shared__ float yt[16][196];
    __shared__ float red[16][16];
    int l0 = blockIdx.x * 16;
    int t = threadIdx.x;
    int l = t & 15, g = t >> 4;
    int d0 = g * 12;
    // stage 4-direction sum
    float psum = 0.f;
#pragma unroll
    for (int j = 0; j < 12; ++j) {
        int d = d0 + j;
        float y = scan_y[(0 * DI_ + d) * L_ + l0 + l]
                + scan_y[(1 * DI_ + d) * L_ + l0 + l]
                + scan_y[(2 * DI_ + d) * L_ + l0 + l]
                + scan_y[(3 * DI_ + d) * L_ + l0 + l];
        yt[l][d] = y;
        psum += y;
    }
    red[g][l] = psum;
    __syncthreads();
    float mu = 0.f;
#pragma unroll
    for (int g2 = 0; g2 < 16; ++g2) mu += red[g2][l];
    mu *= (1.f / DI_);
    float pv = 0.f;
#pragma unroll
    for (int j = 0; j < 12; ++j) {
        float yc = yt[l][d0 + j] - mu;
        pv += yc * yc;
    }
    __syncthreads();
    red[g][l] = pv;
    __syncthreads();
    float var = 0.f;
#pragma unroll
    for (int g2 = 0; g2 < 16; ++g2) var += red[g2][l];
    var *= (1.f / DI_);
    float rstd = rsqrtf(var + 1e-5f);
#pragma unroll
    for (int j = 0; j < 12; ++j) {
        int d = d0 + j;
        float zv = xzT[(DI_ + d) * L_ + l0 + l];
        float yn = (yt[l][d] - mu) * rstd * onw[d] + onb[d];
        yt[l][d] = yn * sp_silu(zv);
    }
    __syncthreads();
    // out_proj: c in [g*6, g*6+6), d-vectorized
    int c0 = g * 6;
    float acc[6] = {0.f, 0.f, 0.f, 0.f, 0.f, 0.f};
    for (int dd = 0; dd < DI_; dd += 4) {
        float4 yv = *(const float4*)&yt[l][dd];
#pragma unroll
        for (int j = 0; j < 6; ++j) {
            float4 wv = *(const float4*)&Wout[(c0 + j) * DI_ + dd];
            acc[j] += yv.x * wv.x + yv.y * wv.y + yv.z * wv.z + yv.w * wv.w;
        }
    }
    float ss = 0.f;
    float x2v[6];
#pragma unroll
    for (int j = 0; j < 6; ++j) {
        int c = c0 + j;
        float v = x[c * L_ + l0 + l] + acc[j];
        x2v[j] = v; ss += v * v;
        x2[c * L_ + l0 + l] = v;
    }
    __syncthreads();
    red[g][l] = ss;
    __syncthreads();
    float tot = 0.f;
#pragma unroll
    for (int g2 = 0; g2 < 16; ++g2) tot += red[g2][l];
    float r2 = rsqrtf(tot * (1.f / C96) + 1e-6f);
#pragma unroll
    for (int j = 0; j < 6; ++j) {
        int c = c0 + j;
        n2[c * L_ + l0 + l] = x2v[j] * r2 * w2[c] + b2[c];
    }
}

// K12: EDFFN pin GEMM: hf[o, l] = sum_c n2[c,l] * W[o,c].  O=510.
__global__ void k_pin(const float* __restrict__ n2, const float* __restrict__ W,
                      float* __restrict__ hf) {
    int l = blockIdx.x * 64 + threadIdx.x;
    int g = blockIdx.y * 4 + threadIdx.y;
    if (g >= 51) return;
    int o0 = g * 10;
    float acc[10] = {0.f, 0.f, 0.f, 0.f, 0.f, 0.f, 0.f, 0.f, 0.f, 0.f};
    for (int c = 0; c < C96; ++c) {
        float v = n2[c * L_ + l];
#pragma unroll
        for (int j = 0; j < 10; ++j) acc[j] += v * W[(o0 + j) * C96 + c];
    }
#pragma unroll
    for (int j = 0; j < 10; ++j) hf[(o0 + j) * L_ + l] = acc[j];
}

// K13: depthwise 3x3 (no bias) on 510 channels + GELU(h1)*h2 gate.
__global__ void k_ffnconv(const float* __restrict__ hf, const float* __restrict__ w,
                          float* __restrict__ g) {
    int idx = blockIdx.x * 256 + threadIdx.x;
    if (idx >= HF_ * L_) return;
    int c = idx / L_, l = idx % L_;
    int h = l >> 6, wc = l & 63;
    float s1 = 0.f, s2 = 0.f;
#pragma unroll
    for (int di = -1; di <= 1; ++di)
#pragma unroll
        for (int dj = -1; dj <= 1; ++dj) {
            int hh = h + di, ww = wc + dj;
            if (hh >= 0 && hh < HW_ && ww >= 0 && ww < HW_) {
                int p = hh * HW_ + ww;
                int widx = (di + 1) * 3 + (dj + 1);
                s1 += hf[c * L_ + p] * w[c * 9 + widx];
                s2 += hf[(c + HF_) * L_ + p] * w[(c + HF_) * 9 + widx];
            }
        }
    float ge = 0.5f * s1 * (1.f + erff(s1 * 0.70710678118654752f));
    g[idx] = ge * s2;
}

// K14: pout GEMM + final residual.
__global__ void k_pout(const float* __restrict__ g, const float* __restrict__ W,
                       const float* __restrict__ x2, float* __restrict__ out) {
    int l = blockIdx.x * 64 + threadIdx.x;
    int c0 = (blockIdx.y * 4 + threadIdx.y) * 8;
    float acc[8] = {0.f, 0.f, 0.f, 0.f, 0.f, 0.f, 0.f, 0.f};
    for (int i = 0; i < HF_; ++i) {
        float v = g[i * L_ + l];
#pragma unroll
        for (int j = 0; j < 8; ++j) acc[j] += v * W[(c0 + j) * HF_ + i];
    }
#pragma unroll
    for (int j = 0; j < 8; ++j)
        out[(c0 + j) * L_ + l] = x2[(c0 + j) * L_ + l] + acc[j];
}

extern "C" void kernel_launch(void* const* d_in, const int* in_sizes, int n_in,
                              void* d_out, int out_size, void* d_ws, size_t ws_size,
                              hipStream_t stream) {
    const float* x         = (const float*)d_in[0];
    const float* norm1_w   = (const float*)d_in[1];
    const float* norm1_b   = (const float*)d_in[2];
    const float* in_proj_w = (const float*)d_in[3];
    const float* conv2d_w  = (const float*)d_in[4];
    const float* conv2d_b  = (const float*)d_in[5];
    const float* x_proj_w  = (const float*)d_in[6];
    const float* dt_projs_w= (const float*)d_in[7];
    const float* dt_projs_b= (const float*)d_in[8];
    const float* A_logs    = (const float*)d_in[9];
    const float* Ds        = (const float*)d_in[10];
    const float* out_norm_w= (const float*)d_in[11];
    const float* out_norm_b= (const float*)d_in[12];
    const float* out_proj_w= (const float*)d_in[13];
    const float* norm2_w   = (const float*)d_in[14];
    const float* norm2_b   = (const float*)d_in[15];
    const float* pin_w     = (const float*)d_in[16];
    const float* dw_w      = (const float*)d_in[17];
    const float* pout_w    = (const float*)d_in[18];

    float* ws = (float*)d_ws;
    float* n1     = ws; ws += C96 * L_;          // reused as dtsb after inproj
    float* xzT    = ws; ws += 2 * DI_ * L_;
    float* xconv  = ws; ws += DI_ * L_;
    float* xs     = ws; ws += Kk * DI_ * L_;     // reused as hf after scan3
    float* delta  = ws; ws += Kk * DI_ * L_;     // reused as gbuf after scan3
    float* BsT    = ws; ws += Kk * L_ * Nn;
    float* CsT    = ws; ws += Kk * L_ * Nn;
    float* Pw     = ws; ws += Kk * DI_ * NCH_ * Nn;
    float* Sw     = ws; ws += Kk * DI_ * NCH_ * Nn;
    float* HS     = ws; ws += Kk * DI_ * NCH_ * Nn;
    float* scan_y = ws; ws += Kk * DI_ * L_;
    float* x2     = ws; ws += C96 * L_;
    float* n2     = ws; ws += C96 * L_;
    float* dtsb   = n1;
    float* hf     = xs;
    float* gbuf   = delta;

    dim3 b64x4(64, 4, 1);

    k_rmsln1<<<256, 256, 0, stream>>>(x, norm1_w, norm1_b, n1);
    k_inproj<<<dim3(64, 12), b64x4, 0, stream>>>(n1, in_proj_w, xzT);
    k_conv192<<<3072, 256, 0, stream>>>(xzT, conv2d_w, conv2d_b, xconv);
    k_build_xs<<<12288, 256, 0, stream>>>(xconv, xs);
    k_xdbl2<<<dim3(64, 4), 256, 0, stream>>>(xs, x_proj_w, dtsb, BsT, CsT);
    k_delta<<<12288, 256, 0, stream>>>(dtsb, dt_projs_w, dt_projs_b, delta);
    k_scan1<<<768, 256, 0, stream>>>(delta, xs, BsT, A_logs, Pw, Sw);
    k_scan2<<<48, 256, 0, stream>>>(Pw, Sw, HS);
    k_scan3<<<768, 256, 0, stream>>>(delta, xs, BsT, CsT, A_logs, Ds, HS, scan_y);
    k_combine3<<<256, 256, 0, stream>>>(scan_y, out_norm_w, out_norm_b, xzT,
                                        out_proj_w, x, norm2_w, norm2_b, x2, n2);
    k_pin<<<dim3(64, 13), b64x4, 0, stream>>>(n2, pin_w, hf);
    k_ffnconv<<<4080, 256, 0, stream>>>(hf, dw_w, gbuf);
    k_pout<<<dim3(64, 3), b64x4, 0, stream>>>(gbuf, pout_w, x2, (float*)d_out);
}

// Round 6
// 273.192 us; speedup vs baseline: 1.2805x; 1.1095x over previous
//
#include <hip/hip_runtime.h>
#include <hip/hip_bf16.h>
#include <math.h>

#define L_    4096
#define C96   96
#define DI_   192
#define Nn    16
#define Rr    6
#define Kk    4
#define HW_   64
#define HF_   255

__device__ __forceinline__ float sp_softplus(float s) {
    return fmaxf(s, 0.f) + log1pf(expf(-fabsf(s)));
}
__device__ __forceinline__ float sp_silu(float s) {
    return s / (1.f + expf(-s));
}
// quad-perm DPP shuffles (full-rate VALU, lanes within quad)
__device__ __forceinline__ float qxor1(float x) {
    return __int_as_float(__builtin_amdgcn_update_dpp(0, __float_as_int(x),
                                                      0xB1, 0xF, 0xF, true));
}
__device__ __forceinline__ float qxor2(float x) {
    return __int_as_float(__builtin_amdgcn_update_dpp(0, __float_as_int(x),
                                                      0x4E, 0xF, 0xF, true));
}

// K1: RMS-LN, l-tile=16, 16 groups x 6 channels. grid=256.
__global__ __launch_bounds__(256) void k_rmsln1(const float* __restrict__ x,
        const float* __restrict__ w, const float* __restrict__ b,
        float* __restrict__ n1) {
    __shared__ float red[16][16];
    int l0 = blockIdx.x * 16;
    int t = threadIdx.x;
    int l = t & 15, g = t >> 4;
    float xv[6];
    float ss = 0.f;
#pragma unroll
    for (int j = 0; j < 6; ++j) {
        int c = g * 6 + j;
        xv[j] = x[c * L_ + l0 + l];
        ss += xv[j] * xv[j];
    }
    red[g][l] = ss;
    __syncthreads();
    float tot = 0.f;
#pragma unroll
    for (int g2 = 0; g2 < 16; ++g2) tot += red[g2][l];
    float r = rsqrtf(tot * (1.f / C96) + 1e-6f);
#pragma unroll
    for (int j = 0; j < 6; ++j) {
        int c = g * 6 + j;
        n1[c * L_ + l0 + l] = xv[j] * r * w[c] + b[c];
    }
}

// K2: in_proj GEMM: xzT[o, l] = sum_c n1[c,l] * W[o,c].  O=384. 8-way o blocking.
__global__ void k_inproj(const float* __restrict__ n1, const float* __restrict__ W,
                         float* __restrict__ xzT) {
    int l = blockIdx.x * 64 + threadIdx.x;
    int o0 = (blockIdx.y * 4 + threadIdx.y) * 8;
    float acc[8] = {0.f, 0.f, 0.f, 0.f, 0.f, 0.f, 0.f, 0.f};
    for (int c = 0; c < C96; ++c) {
        float v = n1[c * L_ + l];
#pragma unroll
        for (int j = 0; j < 8; ++j) acc[j] += v * W[(o0 + j) * C96 + c];
    }
#pragma unroll
    for (int j = 0; j < 8; ++j) xzT[(o0 + j) * L_ + l] = acc[j];
}

// K3: depthwise 3x3 conv (SAME) + bias + SiLU on xc (192, 64, 64).
__global__ void k_conv192(const float* __restrict__ xc, const float* __restrict__ w,
                          const float* __restrict__ b, float* __restrict__ out) {
    int idx = blockIdx.x * 256 + threadIdx.x;
    if (idx >= DI_ * L_) return;
    int c = idx / L_, l = idx % L_;
    int h = l >> 6, wc = l & 63;
    float s = b[c];
#pragma unroll
    for (int di = -1; di <= 1; ++di)
#pragma unroll
        for (int dj = -1; dj <= 1; ++dj) {
            int hh = h + di, ww = wc + dj;
            if (hh >= 0 && hh < HW_ && ww >= 0 && ww < HW_)
                s += xc[c * L_ + hh * HW_ + ww] * w[c * 9 + (di + 1) * 3 + (dj + 1)];
        }
    out[idx] = sp_silu(s);
}

// K4: materialize 4 direction views xs[(k*DI+d)*L + l]
__global__ void k_build_xs(const float* __restrict__ xconv, float* __restrict__ xs) {
    int idx = blockIdx.x * 256 + threadIdx.x;
    if (idx >= Kk * DI_ * L_) return;
    int l = idx % L_; int kd = idx / L_; int d = kd % DI_; int k = kd / DI_;
    int ll = (k & 2) ? (L_ - 1 - l) : l;
    int pos = (k & 1) ? ((ll & 63) * 64 + (ll >> 6)) : ll;
    xs[idx] = xconv[d * L_ + pos];
}

// K5: x_proj GEMM fused with B/C transpose. Block=256: one k, 64-wide l tile.
__global__ __launch_bounds__(256) void k_xdbl2(const float* __restrict__ xs,
        const float* __restrict__ Wxp, float* __restrict__ dts,
        float* __restrict__ BsT, float* __restrict__ CsT) {
    __shared__ float sx[DI_][64];
    int k = blockIdx.y;
    int l0 = blockIdx.x * 64;
    int t = threadIdx.x;
    const float* src = xs + (k * DI_) * L_ + l0;
    for (int i = t; i < DI_ * 64; i += 256) {
        int d = i >> 6, l = i & 63;
        sx[d][l] = src[d * L_ + l];
    }
    __syncthreads();
    int l = t & 63, cg = t >> 6;
    int c0 = cg * 10;
    int cnt = (cg == 3) ? 8 : 10;
    float acc[10] = {0.f, 0.f, 0.f, 0.f, 0.f, 0.f, 0.f, 0.f, 0.f, 0.f};
    const float* Wk = Wxp + k * 38 * DI_;
    for (int d = 0; d < DI_; ++d) {
        float v = sx[d][l];
#pragma unroll
        for (int j = 0; j < 10; ++j) {
            int cj = c0 + j; if (cj > 37) cj = 37;
            acc[j] += v * Wk[cj * DI_ + d];
        }
    }
    int gl = l0 + l;
#pragma unroll
    for (int j = 0; j < 10; ++j) {
        if (j < cnt) {
            int c = c0 + j;
            float v = acc[j];
            if (c < Rr)           dts[(k * Rr + c) * L_ + gl] = v;
            else if (c < Rr + Nn) BsT[(k * L_ + gl) * Nn + (c - Rr)] = v;
            else                  CsT[(k * L_ + gl) * Nn + (c - Rr - Nn)] = v;
        }
    }
}

// K6: delta[kd, l] = softplus(sum_r dts[k,r,l] * dtw[kd,r] + dtb[kd])
__global__ void k_delta(const float* __restrict__ dts, const float* __restrict__ dtw,
                        const float* __restrict__ dtb, float* __restrict__ delta) {
    int idx = blockIdx.x * 256 + threadIdx.x;
    if (idx >= Kk * DI_ * L_) return;
    int l = idx % L_; int kd = idx / L_; int k = kd / DI_;
    float s = dtb[kd];
#pragma unroll
    for (int r = 0; r < Rr; ++r)
        s += dts[(k * Rr + r) * L_ + l] * dtw[kd * Rr + r];
    delta[idx] = sp_softplus(s);
}

// K8v3: FUSED selective scan. One block per kd (grid=768, 256 thr).
// Stage delta/u rows in LDS (pad-65) -> phase A chunk scan (64 chunks x
// 4 lanes x 4 n) -> Kogge-Stone prefix over chunks in LDS -> phase C
// replay depositing y into LDS -> coalesced direction-mapped writeout.
__global__ __launch_bounds__(256) void k_scan(const float* __restrict__ delta,
        const float* __restrict__ xs, const float* __restrict__ BsT,
        const float* __restrict__ CsT, const float* __restrict__ A_logs,
        const float* __restrict__ Ds, float* __restrict__ scan_y) {
    __shared__ float dl_s[64 * 65];
    __shared__ float u_s[64 * 65];
    __shared__ float ys[64 * 65];
    __shared__ float Pl[64][16];
    __shared__ float Sl[64][16];
    int kd = blockIdx.x; int k = kd / DI_;
    int t = threadIdx.x;
    {
        const float4* dg = (const float4*)(delta + kd * L_);
        const float4* ug = (const float4*)(xs + kd * L_);
        for (int s = t; s < 1024; s += 256) {
            float4 dv = dg[s], uv = ug[s];
            int o = (s >> 4) * 65 + ((s << 2) & 63);
            dl_s[o] = dv.x; dl_s[o + 1] = dv.y; dl_s[o + 2] = dv.z; dl_s[o + 3] = dv.w;
            u_s[o] = uv.x;  u_s[o + 1] = uv.y;  u_s[o + 2] = uv.z;  u_s[o + 3] = uv.w;
        }
    }
    int g = t >> 2, j = t & 3;
    float4 Al = *(const float4*)&A_logs[kd * Nn + 4 * j];
    float A0 = -__expf(Al.x), A1 = -__expf(Al.y), A2 = -__expf(Al.z), A3 = -__expf(Al.w);
    __syncthreads();
    int lo = g * 65;
    const float4* Bv = (const float4*)&BsT[(k * L_ + g * 64) * Nn + 4 * j];
    const float4* Cv = (const float4*)&CsT[(k * L_ + g * 64) * Nn + 4 * j];
    // phase A: chunk-local scan, h0 = 0
    float h0 = 0.f, h1 = 0.f, h2 = 0.f, h3 = 0.f;
    float p0 = 1.f, p1 = 1.f, p2 = 1.f, p3 = 1.f;
    for (int i = 0; i < 64; ++i) {
        float dl = dl_s[lo + i], ul = u_s[lo + i];
        float4 bv = Bv[i * 4];
        float du = dl * ul;
        float e0 = __expf(dl * A0), e1 = __expf(dl * A1);
        float e2 = __expf(dl * A2), e3 = __expf(dl * A3);
        h0 = e0 * h0 + du * bv.x; h1 = e1 * h1 + du * bv.y;
        h2 = e2 * h2 + du * bv.z; h3 = e3 * h3 + du * bv.w;
        p0 *= e0; p1 *= e1; p2 *= e2; p3 *= e3;
    }
    *(float4*)&Pl[g][4 * j] = make_float4(p0, p1, p2, p3);
    *(float4*)&Sl[g][4 * j] = make_float4(h0, h1, h2, h3);
    __syncthreads();
    // Kogge-Stone inclusive scan over 64 chunks
    for (int s = 1; s < 64; s <<= 1) {
        float4 pp, sp;
        bool act = (g >= s);
        if (act) {
            pp = *(float4*)&Pl[g - s][4 * j];
            sp = *(float4*)&Sl[g - s][4 * j];
        }
        __syncthreads();
        if (act) {
            float4 pc = *(float4*)&Pl[g][4 * j];
            float4 sc = *(float4*)&Sl[g][4 * j];
            *(float4*)&Pl[g][4 * j] =
                make_float4(pp.x * pc.x, pp.y * pc.y, pp.z * pc.z, pp.w * pc.w);
            *(float4*)&Sl[g][4 * j] =
                make_float4(pc.x * sp.x + sc.x, pc.y * sp.y + sc.y,
                            pc.z * sp.z + sc.z, pc.w * sp.w + sc.w);
        }
        __syncthreads();
    }
    // phase C: replay with exclusive prefix h0
    float4 hv = make_float4(0.f, 0.f, 0.f, 0.f);
    if (g > 0) hv = *(const float4*)&Sl[g - 1][4 * j];
    float Dp = Ds[kd];
    h0 = hv.x; h1 = hv.y; h2 = hv.z; h3 = hv.w;
    for (int i = 0; i < 64; ++i) {
        float dl = dl_s[lo + i], ul = u_s[lo + i];
        float4 bv = Bv[i * 4];
        float4 cv = Cv[i * 4];
        float du = dl * ul;
        float e0 = __expf(dl * A0), e1 = __expf(dl * A1);
        float e2 = __expf(dl * A2), e3 = __expf(dl * A3);
        h0 = e0 * h0 + du * bv.x; h1 = e1 * h1 + du * bv.y;
        h2 = e2 * h2 + du * bv.z; h3 = e3 * h3 + du * bv.w;
        float ps = h0 * cv.x + h1 * cv.y + h2 * cv.z + h3 * cv.w;
        ps += qxor1(ps);
        ps += qxor2(ps);
        if (j == 0) ys[lo + i] = ps + Dp * ul;
    }
    __syncthreads();
    // coalesced writeout in ORIGINAL image coordinates (inverse map)
    float* yout = scan_y + kd * L_;
    for (int p = t; p < L_; p += 256) {
        int ll = (k & 1) ? (((p & 63) << 6) | (p >> 6)) : p;
        int sl = (k & 2) ? (L_ - 1 - ll) : ll;
        yout[p] = ys[sl + (sl >> 6)];
    }
}

// K11: l-tile=16, grid=256 blocks, 256 threads = 16 groups x 16 lanes.
__global__ __launch_bounds__(256) void k_combine3(
        const float* __restrict__ scan_y, const float* __restrict__ onw,
        const float* __restrict__ onb, const float* __restrict__ xzT,
        const float* __restrict__ Wout, const float* __restrict__ x,
        const float* __restrict__ w2, const float* __restrict__ b2,
        float* __restrict__ x2, float* __restrict__ n2) {
    __shared__ float yt[16][196];
    __shared__ float red[16][16];
    int l0 = blockIdx.x * 16;
    int t = threadIdx.x;
    int l = t & 15, g = t >> 4;
    int d0 = g * 12;
    float psum = 0.f;
#pragma unroll
    for (int j = 0; j < 12; ++j) {
        int d = d0 + j;
        float y = scan_y[(0 * DI_ + d) * L_ + l0 + l]
                + scan_y[(1 * DI_ + d) * L_ + l0 + l]
                + scan_y[(2 * DI_ + d) * L_ + l0 + l]
                + scan_y[(3 * DI_ + d) * L_ + l0 + l];
        yt[l][d] = y;
        psum += y;
    }
    red[g][l] = psum;
    __syncthreads();
    float mu = 0.f;
#pragma unroll
    for (int g2 = 0; g2 < 16; ++g2) mu += red[g2][l];
    mu *= (1.f / DI_);
    float pv = 0.f;
#pragma unroll
    for (int j = 0; j < 12; ++j) {
        float yc = yt[l][d0 + j] - mu;
        pv += yc * yc;
    }
    __syncthreads();
    red[g][l] = pv;
    __syncthreads();
    float var = 0.f;
#pragma unroll
    for (int g2 = 0; g2 < 16; ++g2) var += red[g2][l];
    var *= (1.f / DI_);
    float rstd = rsqrtf(var + 1e-5f);
#pragma unroll
    for (int j = 0; j < 12; ++j) {
        int d = d0 + j;
        float zv = xzT[(DI_ + d) * L_ + l0 + l];
        float yn = (yt[l][d] - mu) * rstd * onw[d] + onb[d];
        yt[l][d] = yn * sp_silu(zv);
    }
    __syncthreads();
    int c0 = g * 6;
    float acc[6] = {0.f, 0.f, 0.f, 0.f, 0.f, 0.f};
    for (int dd = 0; dd < DI_; dd += 4) {
        float4 yv = *(const float4*)&yt[l][dd];
#pragma unroll
        for (int j = 0; j < 6; ++j) {
            float4 wv = *(const float4*)&Wout[(c0 + j) * DI_ + dd];
            acc[j] += yv.x * wv.x + yv.y * wv.y + yv.z * wv.z + yv.w * wv.w;
        }
    }
    float ss = 0.f;
    float x2v[6];
#pragma unroll
    for (int j = 0; j < 6; ++j) {
        int c = c0 + j;
        float v = x[c * L_ + l0 + l] + acc[j];
        x2v[j] = v; ss += v * v;
        x2[c * L_ + l0 + l] = v;
    }
    __syncthreads();
    red[g][l] = ss;
    __syncthreads();
    float tot = 0.f;
#pragma unroll
    for (int g2 = 0; g2 < 16; ++g2) tot += red[g2][l];
    float r2 = rsqrtf(tot * (1.f / C96) + 1e-6f);
#pragma unroll
    for (int j = 0; j < 6; ++j) {
        int c = c0 + j;
        n2[c * L_ + l0 + l] = x2v[j] * r2 * w2[c] + b2[c];
    }
}

// K12: EDFFN pin GEMM: hf[o, l] = sum_c n2[c,l] * W[o,c].  O=510.
__global__ void k_pin(const float* __restrict__ n2, const float* __restrict__ W,
                      float* __restrict__ hf) {
    int l = blockIdx.x * 64 + threadIdx.x;
    int g = blockIdx.y * 4 + threadIdx.y;
    if (g >= 51) return;
    int o0 = g * 10;
    float acc[10] = {0.f, 0.f, 0.f, 0.f, 0.f, 0.f, 0.f, 0.f, 0.f, 0.f};
    for (int c = 0; c < C96; ++c) {
        float v = n2[c * L_ + l];
#pragma unroll
        for (int j = 0; j < 10; ++j) acc[j] += v * W[(o0 + j) * C96 + c];
    }
#pragma unroll
    for (int j = 0; j < 10; ++j) hf[(o0 + j) * L_ + l] = acc[j];
}

// K13: depthwise 3x3 (no bias) on 510 channels + GELU(h1)*h2 gate.
__global__ void k_ffnconv(const float* __restrict__ hf, const float* __restrict__ w,
                          float* __restrict__ g) {
    int idx = blockIdx.x * 256 + threadIdx.x;
    if (idx >= HF_ * L_) return;
    int c = idx / L_, l = idx % L_;
    int h = l >> 6, wc = l & 63;
    float s1 = 0.f, s2 = 0.f;
#pragma unroll
    for (int di = -1; di <= 1; ++di)
#pragma unroll
        for (int dj = -1; dj <= 1; ++dj) {
            int hh = h + di, ww = wc + dj;
            if (hh >= 0 && hh < HW_ && ww >= 0 && ww < HW_) {
                int p = hh * HW_ + ww;
                int widx = (di + 1) * 3 + (dj + 1);
                s1 += hf[c * L_ + p] * w[c * 9 + widx];
                s2 += hf[(c + HF_) * L_ + p] * w[(c + HF_) * 9 + widx];
            }
        }
    float ge = 0.5f * s1 * (1.f + erff(s1 * 0.70710678118654752f));
    g[idx] = ge * s2;
}

// K14: pout GEMM + final residual.
__global__ void k_pout(const float* __restrict__ g, const float* __restrict__ W,
                       const float* __restrict__ x2, float* __restrict__ out) {
    int l = blockIdx.x * 64 + threadIdx.x;
    int c0 = (blockIdx.y * 4 + threadIdx.y) * 8;
    float acc[8] = {0.f, 0.f, 0.f, 0.f, 0.f, 0.f, 0.f, 0.f};
    for (int i = 0; i < HF_; ++i) {
        float v = g[i * L_ + l];
#pragma unroll
        for (int j = 0; j < 8; ++j) acc[j] += v * W[(c0 + j) * HF_ + i];
    }
#pragma unroll
    for (int j = 0; j < 8; ++j)
        out[(c0 + j) * L_ + l] = x2[(c0 + j) * L_ + l] + acc[j];
}

extern "C" void kernel_launch(void* const* d_in, const int* in_sizes, int n_in,
                              void* d_out, int out_size, void* d_ws, size_t ws_size,
                              hipStream_t stream) {
    const float* x         = (const float*)d_in[0];
    const float* norm1_w   = (const float*)d_in[1];
    const float* norm1_b   = (const float*)d_in[2];
    const float* in_proj_w = (const float*)d_in[3];
    const float* conv2d_w  = (const float*)d_in[4];
    const float* conv2d_b  = (const float*)d_in[5];
    const float* x_proj_w  = (const float*)d_in[6];
    const float* dt_projs_w= (const float*)d_in[7];
    const float* dt_projs_b= (const float*)d_in[8];
    const float* A_logs    = (const float*)d_in[9];
    const float* Ds        = (const float*)d_in[10];
    const float* out_norm_w= (const float*)d_in[11];
    const float* out_norm_b= (const float*)d_in[12];
    const float* out_proj_w= (const float*)d_in[13];
    const float* norm2_w   = (const float*)d_in[14];
    const float* norm2_b   = (const float*)d_in[15];
    const float* pin_w     = (const float*)d_in[16];
    const float* dw_w      = (const float*)d_in[17];
    const float* pout_w    = (const float*)d_in[18];

    float* ws = (float*)d_ws;
    float* n1     = ws; ws += C96 * L_;          // reused as dtsb after inproj
    float* xzT    = ws; ws += 2 * DI_ * L_;
    float* xconv  = ws; ws += DI_ * L_;
    float* xs     = ws; ws += Kk * DI_ * L_;     // reused as hf after scan
    float* delta  = ws; ws += Kk * DI_ * L_;     // reused as gbuf after scan
    float* BsT    = ws; ws += Kk * L_ * Nn;
    float* CsT    = ws; ws += Kk * L_ * Nn;
    float* scan_y = ws; ws += Kk * DI_ * L_;
    float* x2     = ws; ws += C96 * L_;
    float* n2     = ws; ws += C96 * L_;
    float* dtsb   = n1;
    float* hf     = xs;
    float* gbuf   = delta;

    dim3 b64x4(64, 4, 1);

    k_rmsln1<<<256, 256, 0, stream>>>(x, norm1_w, norm1_b, n1);
    k_inproj<<<dim3(64, 12), b64x4, 0, stream>>>(n1, in_proj_w, xzT);
    k_conv192<<<3072, 256, 0, stream>>>(xzT, conv2d_w, conv2d_b, xconv);
    k_build_xs<<<12288, 256, 0, stream>>>(xconv, xs);
    k_xdbl2<<<dim3(64, 4), 256, 0, stream>>>(xs, x_proj_w, dtsb, BsT, CsT);
    k_delta<<<12288, 256, 0, stream>>>(dtsb, dt_projs_w, dt_projs_b, delta);
    k_scan<<<768, 256, 0, stream>>>(delta, xs, BsT, CsT, A_logs, Ds, scan_y);
    k_combine3<<<256, 256, 0, stream>>>(scan_y, out_norm_w, out_norm_b, xzT,
                                        out_proj_w, x, norm2_w, norm2_b, x2, n2);
    k_pin<<<dim3(64, 13), b64x4, 0, stream>>>(n2, pin_w, hf);
    k_ffnconv<<<4080, 256, 0, stream>>>(hf, dw_w, gbuf);
    k_pout<<<dim3(64, 3), b64x4, 0, stream>>>(gbuf, pout_w, x2, (float*)d_out);
}